// Round 9
// baseline (2319.406 us; speedup 1.0000x reference)
//
#include <hip/hip_runtime.h>
#include <stdint.h>
#include <stddef.h>

#define NB 1024
#define TB 1024
#define D_IN 6
#define UNITS 64
#define WIDTH 128
#define DOUT 6
#define EPSF 1e-8f
#define SPB 16          // samples per block (one 16-row MFMA tile) -- 64 blocks
#define LDK0 108        // c0 row stride (halfs): conflict-free (54 dw == 22 mod 32)
#define LDK 140         // cP/cQ/cG row stride (halfs): conflict-free (70 dw == 6 mod 32)

typedef _Float16 v8h __attribute__((ext_vector_type(8)));
typedef float v4f __attribute__((ext_vector_type(4)));
typedef float v2f __attribute__((ext_vector_type(2)));

#define MFMAH(A,Bf,C) __builtin_amdgcn_mfma_f32_16x16x32_f16((A),(Bf),(C),0,0,0)

// LDS-only barrier: orders LDS across the block, does NOT drain vmcnt.
#define BARRIER_LDS() asm volatile("s_waitcnt lgkmcnt(0)\n\ts_barrier" ::: "memory")

#define C2L2E  2.8853900817779268f    // 2*log2(e)
#define L2E    1.4426950408889634f    // log2(e)
#define NEGL2E (-1.4426950408889634f)

__device__ __forceinline__ float rcp_fast(float x){ return __builtin_amdgcn_rcpf(x); }

// tanh with the 2log2e factor PRE-FOLDED into weights+bias:
// tanh(y) = 1 - 2/(1 + 2^(y*2log2e)); caller passes a2 = y*2log2e (from MFMA).
__device__ __forceinline__ float tanh_from_arg(float a2){
  float u = __builtin_amdgcn_exp2f(a2);
  return fmaf(-2.0f, rcp_fast(u + 1.0f), 1.0f);
}

__device__ __forceinline__ void make_frag1(const float* vals, v8h& hv){
  #pragma unroll
  for (int j = 0; j < 8; j++) hv[j] = (_Float16)vals[j];
}
__device__ __forceinline__ void make_frag2(const float* vals, v8h& hv, v8h& lv){
  #pragma unroll
  for (int j = 0; j < 8; j++){
    _Float16 h = (_Float16)vals[j];
    hv[j] = h;
    lv[j] = (_Float16)(vals[j] - (float)h);
  }
}

__global__ __launch_bounds__(512, 2) void lmsc_kernel(
    const float* __restrict__ x, const float* __restrict__ initF,
    const float* __restrict__ w10, const float* __restrict__ b10,
    const float* __restrict__ w20, const float* __restrict__ b20,
    const float* __restrict__ w11, const float* __restrict__ b11,
    const float* __restrict__ w21, const float* __restrict__ b21,
    const float* __restrict__ w12, const float* __restrict__ b12,
    const float* __restrict__ w22, const float* __restrict__ b22,
    const float* __restrict__ wa, const float* __restrict__ ba,
    const float* __restrict__ wb, const float* __restrict__ bb,
    const float* __restrict__ wo,
    float* __restrict__ outs, float* __restrict__ alph)
{
  // ---- LDS: ~20 KB ----
  __shared__ __attribute__((aligned(16))) _Float16 c0[2][SPB*LDK0];  // t-parity double buffer
  __shared__ __attribute__((aligned(16))) _Float16 cP[SPB*LDK];
  __shared__ __attribute__((aligned(16))) _Float16 cQ[SPB*LDK];
  __shared__ __attribute__((aligned(16))) _Float16 cG[SPB*LDK];
  __shared__ __attribute__((aligned(16))) float nrm[2][SPB];         // stores -log2e * ||x||

  const int tid = threadIdx.x;
  const int wv = tid >> 6;       // wave 0..7
  const int ln = tid & 63;
  const int mn = ln & 15;
  const int qd = ln >> 4;
  const int q8 = qd * 8;
  const int n  = wv * 16 + mn;   // col for WIDTH=128 layers (wave owns 16 cols)
  const int sgbase = (int)blockIdx.x * SPB;

  float tmp[8];

  // ---------------- one-time weight fragments (registers) ----------------
  // All exp2-feeding weights PRE-SCALED so the MFMA emits the exp2 arg directly:
  //   L0/L1 both branches, L2 branch0: * 2log2e;  wa: * log2e;  wb: * 2log2e.
  // f16 rounding is scale-invariant -> no accuracy change.

  // L0: K through c0 cols (xn 0..5, h 8..71), 3 kf
  v8h B0[3][2];
  #pragma unroll
  for (int kf = 0; kf < 3; kf++)
    #pragma unroll
    for (int br = 0; br < 2; br++){
      const float* W = br ? w20 : w10;
      #pragma unroll
      for (int j = 0; j < 8; j++){
        int k = kf*32 + q8 + j;
        int r = (k < 6) ? k : ((k >= 8 && k < 72) ? (k - 2) : -1);
        tmp[j] = (r >= 0) ? W[r*WIDTH + n] * C2L2E : 0.0f;
      }
      make_frag1(tmp, B0[kf][br]);
    }

  // L1 (both branches *2log2e), L2 (branch0 *2log2e, branch1 raw)
  v8h B1[4][2], B2[4][2];
  #pragma unroll
  for (int kf = 0; kf < 4; kf++)
    #pragma unroll
    for (int br = 0; br < 2; br++){
      const float* W = br ? w21 : w11;
      #pragma unroll
      for (int j = 0; j < 8; j++)
        tmp[j] = W[(kf*32 + q8 + j)*WIDTH + n] * C2L2E;
      make_frag1(tmp, B1[kf][br]);
      const float* V = br ? w22 : w12;
      const float sc = br ? 1.0f : C2L2E;
      #pragma unroll
      for (int j = 0; j < 8; j++)
        tmp[j] = V[(kf*32 + q8 + j)*WIDTH + n] * sc;
      make_frag1(tmp, B2[kf][br]);
    }

  // D-phase: wave (wv&3) owns units u..u+15; wa hi+lo (*log2e), wb single (*2log2e)
  const int u = (wv & 3) * 16 + mn;
  v8h Bah[4], Bal[4], Bbh[4];
  #pragma unroll
  for (int kf = 0; kf < 4; kf++){
    #pragma unroll
    for (int j = 0; j < 8; j++)
      tmp[j] = wa[(kf*32 + q8 + j)*UNITS + u] * L2E;
    make_frag2(tmp, Bah[kf], Bal[kf]);
    #pragma unroll
    for (int j = 0; j < 8; j++)
      tmp[j] = wb[(kf*32 + q8 + j)*UNITS + u] * C2L2E;
    make_frag1(tmp, Bbh[kf]);
  }

  // wout (K=64 over h, N=6 padded to 16): single fp16 (used by wave 7)
  v8h Woh0, Woh1;
  #pragma unroll
  for (int j = 0; j < 8; j++)
    tmp[j] = (mn < DOUT) ? wo[(q8 + j)*DOUT + mn] : 0.0f;
  make_frag1(tmp, Woh0);
  #pragma unroll
  for (int j = 0; j < 8; j++)
    tmp[j] = (mn < DOUT) ? wo[(32 + q8 + j)*DOUT + mn] : 0.0f;
  make_frag1(tmp, Woh1);

  // biases as LOOP-INVARIANT v4f splats, fed directly as the C-operand of the
  // first MFMA of each chain (zero acc-init v_movs in the hot loop).
  const float e0a = b10[n] * C2L2E, e0b = b20[n] * C2L2E;
  const float e1a = b11[n] * C2L2E, e1b = b21[n] * C2L2E;
  const float e2a = b12[n] * C2L2E, e2b = b22[n];
  const v4f E0A = {e0a, e0a, e0a, e0a}, E0B = {e0b, e0b, e0b, e0b};
  const v4f E1A = {e1a, e1a, e1a, e1a}, E1B = {e1b, e1b, e1b, e1b};
  const v4f E2A = {e2a, e2a, e2a, e2a}, E2B = {e2b, e2b, e2b, e2b};
  const float bsa = ba[u] * L2E;     // alpha = exp2(pA)
  const float bsb = bb[u] * C2L2E;   // beta  = tanh_from_arg(pB)
  const v4f BSA4 = {bsa, bsa, bsa, bsa};
  const v4f BSB4 = {bsb, bsb, bsb, bsb};
  const v4f Z4   = {0.f, 0.f, 0.f, 0.f};

  // hoisted global-store bases (loop-invariant 64-bit address math)
  float* alp  = alph + ((size_t)(sgbase + qd*4) * TB) * UNITS + u;          // waves 0-3
  float* outp = outs + ((size_t)(sgbase + qd*4) * TB) * DOUT + mn;          // wave 7

  // ---------------- init ----------------
  for (int i = tid; i < 2*SPB*LDK0; i += 512) c0[0][i] = (_Float16)0.0f;
  __syncthreads();

  // h persistent in registers of waves 0-3 (C-layout: col=unit=u, row=sample=qd*4+r)
  float hreg[4];
  if (wv < 4){
    #pragma unroll
    for (int r = 0; r < 4; r++){
      int s = qd*4 + r;
      float v = initF[(size_t)(sgbase + s)*(2 + UNITS) + 2 + u];
      hreg[r] = v;
      c0[0][s*LDK0 + 8 + u] = (_Float16)v;
    }
  }
  float xv0=0, xv1=0, xv2=0, xv3=0, xv4=0, xv5=0;
  if (wv == 4 && ln < 16){
    const v2f* xp2 = (const v2f*)(x + (size_t)(sgbase + ln)*TB*D_IN);  // rows 24B -> 8B aligned
    v2f A = xp2[0], Bv = xp2[1], C = xp2[2];
    float nv = sqrtf(A[0]*A[0] + A[1]*A[1] + Bv[0]*Bv[0] + Bv[1]*Bv[1] + C[0]*C[0] + C[1]*C[1]);
    nrm[0][ln] = nv * NEGL2E;
    float inv = 1.0f / (nv + EPSF);
    c0[0][ln*LDK0 + 0] = (_Float16)(A[0]*inv);
    c0[0][ln*LDK0 + 1] = (_Float16)(A[1]*inv);
    c0[0][ln*LDK0 + 2] = (_Float16)(Bv[0]*inv);
    c0[0][ln*LDK0 + 3] = (_Float16)(Bv[1]*inv);
    c0[0][ln*LDK0 + 4] = (_Float16)(C[0]*inv);
    c0[0][ln*LDK0 + 5] = (_Float16)(C[1]*inv);
    v2f D = xp2[3], E = xp2[4], F = xp2[5];                            // x(t=1)
    xv0 = D[0]; xv1 = D[1]; xv2 = E[0]; xv3 = E[1]; xv4 = F[0]; xv5 = F[1];
  }
  __syncthreads();

  auto wout_phase = [&](const _Float16* cb, int tt){
    v8h ah0 = *(const v8h*)(cb + mn*LDK0 + 8 + q8);
    v8h ah1 = *(const v8h*)(cb + mn*LDK0 + 40 + q8);
    v4f acc = MFMAH(ah0, Woh0, Z4);
    acc = MFMAH(ah1, Woh1, acc);
    if (mn < DOUT){
      #pragma unroll
      for (int r = 0; r < 4; r++)
        outp[(size_t)r*TB*DOUT + (size_t)tt*DOUT] = acc[r];
    }
  };

  // ---- convoy breaker: each SIMD pairs wave w (prio 1) with wave w+4 (prio 0).
  // Persistent priority skews the two waves' phase execution so one occupies the
  // LDS pipe while the other runs MFMA/VALU, instead of lockstep contention.
  if (wv < 4) __builtin_amdgcn_s_setprio(1);

  // ================= time loop (4 LDS-only barriers/step) =================
  for (int t = 0; t < TB; t++){
    const int p = t & 1;
    const _Float16* c0r = c0[p];
    _Float16* c0w = c0[p ^ 1];

    // ---- Phase A: L0 (c0[p] -> cP) ----
    {
      v8h ah[3];
      #pragma unroll
      for (int kf = 0; kf < 3; kf++)
        ah[kf] = *(const v8h*)(c0r + mn*LDK0 + kf*32 + q8);
      v4f acc0 = MFMAH(ah[0], B0[0][0], E0A);
      v4f acc1 = MFMAH(ah[0], B0[0][1], E0B);
      acc0 = MFMAH(ah[1], B0[1][0], acc0);
      acc1 = MFMAH(ah[1], B0[1][1], acc1);
      acc0 = MFMAH(ah[2], B0[2][0], acc0);
      acc1 = MFMAH(ah[2], B0[2][1], acc1);
      // tanh(y1)*tanh(y2) = (p-s+1)/(p+s+1), u_i = 2^arg_i straight from MFMA.
      #pragma unroll
      for (int r = 0; r < 4; r++){
        float u0 = __builtin_amdgcn_exp2f(acc0[r]);
        float u1 = __builtin_amdgcn_exp2f(acc1[r]);
        float pr = u0 * u1;
        float sm = u0 + u1;
        float pp = pr + 1.0f;
        float res = (pp - sm) * rcp_fast(pp + sm);
        cP[(qd*4 + r)*LDK + n] = (_Float16)res;
      }
    }
    BARRIER_LDS();  // b1

    // ---- Phase B: L1 (cP -> cQ) ----
    {
      v8h ah[4];
      #pragma unroll
      for (int kf = 0; kf < 4; kf++)
        ah[kf] = *(const v8h*)(cP + mn*LDK + kf*32 + q8);
      v4f acc0 = MFMAH(ah[0], B1[0][0], E1A);
      v4f acc1 = MFMAH(ah[0], B1[0][1], E1B);
      acc0 = MFMAH(ah[1], B1[1][0], acc0);
      acc1 = MFMAH(ah[1], B1[1][1], acc1);
      acc0 = MFMAH(ah[2], B1[2][0], acc0);
      acc1 = MFMAH(ah[2], B1[2][1], acc1);
      acc0 = MFMAH(ah[3], B1[3][0], acc0);
      acc1 = MFMAH(ah[3], B1[3][1], acc1);
      #pragma unroll
      for (int r = 0; r < 4; r++){
        float u0 = __builtin_amdgcn_exp2f(acc0[r]);
        float u1 = __builtin_amdgcn_exp2f(acc1[r]);
        float pr = u0 * u1;
        float sm = u0 + u1;
        float pp = pr + 1.0f;
        float res = (pp - sm) * rcp_fast(pp + sm);
        cQ[(qd*4 + r)*LDK + n] = (_Float16)res;
      }
    }
    BARRIER_LDS();  // b2

    // ---- Phase C: L2 (cQ -> g), g = tanh(x1*x2); 2log2e folded into branch0 ----
    {
      v8h ah[4];
      #pragma unroll
      for (int kf = 0; kf < 4; kf++)
        ah[kf] = *(const v8h*)(cQ + mn*LDK + kf*32 + q8);
      v4f acc0 = MFMAH(ah[0], B2[0][0], E2A);
      v4f acc1 = MFMAH(ah[0], B2[0][1], E2B);
      acc0 = MFMAH(ah[1], B2[1][0], acc0);
      acc1 = MFMAH(ah[1], B2[1][1], acc1);
      acc0 = MFMAH(ah[2], B2[2][0], acc0);
      acc1 = MFMAH(ah[2], B2[2][1], acc1);
      acc0 = MFMAH(ah[3], B2[3][0], acc0);
      acc1 = MFMAH(ah[3], B2[3][1], acc1);
      #pragma unroll
      for (int r = 0; r < 4; r++)
        cG[(qd*4 + r)*LDK + n] = (_Float16)tanh_from_arg(acc0[r] * acc1[r]);
    }
    BARRIER_LDS();  // b3

    // ---- Phase D:
    //   waves 0-3: pA (wa hi+lo) + pB for 16 units; h-update in regs;
    //              h(t) -> c0[p^1], alpha -> global (un-drained store)
    //   wave 7:    wout(t-1) from c0[p]
    //   wave 4:    x-norm(t+1) -> c0[p^1], prefetch x(t+2)
    if (wv < 4){
      v8h gh[4];
      #pragma unroll
      for (int kf = 0; kf < 4; kf++)
        gh[kf] = *(const v8h*)(cG + mn*LDK + kf*32 + q8);
      v4f pA0 = MFMAH(gh[0], Bah[0], BSA4);
      v4f pA1 = MFMAH(gh[2], Bah[2], Z4);
      v4f pB  = MFMAH(gh[0], Bbh[0], BSB4);
      pA0 = MFMAH(gh[0], Bal[0], pA0);
      pA1 = MFMAH(gh[2], Bal[2], pA1);
      pB  = MFMAH(gh[1], Bbh[1], pB);
      pA0 = MFMAH(gh[1], Bah[1], pA0);
      pA1 = MFMAH(gh[3], Bah[3], pA1);
      pB  = MFMAH(gh[2], Bbh[2], pB);
      pA0 = MFMAH(gh[1], Bal[1], pA0);
      pA1 = MFMAH(gh[3], Bal[3], pA1);
      pB  = MFMAH(gh[3], Bbh[3], pB);
      #pragma unroll
      for (int r = 0; r < 4; r++){
        int s = qd*4 + r;
        float m = nrm[p][s];                                   // -log2e * norm
        float alpha = __builtin_amdgcn_exp2f(pA0[r] + pA1[r]); // wa,ba pre-scaled
        float beta  = tanh_from_arg(pB[r]);                    // wb,bb pre-scaled
        float dec   = __builtin_amdgcn_exp2f(alpha * m);       // exp(-alpha*norm)
        float h = fmaf(dec, hreg[r] - beta, beta);
        hreg[r] = h;
        c0w[s*LDK0 + 8 + u] = (_Float16)h;
        alp[(size_t)r*TB*UNITS] = alpha;
      }
      alp += UNITS;
    } else if (wv == 7){
      if (t > 0) wout_phase(c0r, t - 1);
    } else if (wv == 4 && ln < 16){
      float nv2 = sqrtf(xv0*xv0 + xv1*xv1 + xv2*xv2 + xv3*xv3 + xv4*xv4 + xv5*xv5);
      nrm[p ^ 1][ln] = nv2 * NEGL2E;
      float inv = 1.0f / (nv2 + EPSF);
      c0w[ln*LDK0 + 0] = (_Float16)(xv0*inv);
      c0w[ln*LDK0 + 1] = (_Float16)(xv1*inv);
      c0w[ln*LDK0 + 2] = (_Float16)(xv2*inv);
      c0w[ln*LDK0 + 3] = (_Float16)(xv3*inv);
      c0w[ln*LDK0 + 4] = (_Float16)(xv4*inv);
      c0w[ln*LDK0 + 5] = (_Float16)(xv5*inv);
      int tn = t + 2; if (tn > TB - 1) tn = TB - 1;
      const v2f* xp2 = (const v2f*)(x + ((size_t)(sgbase + ln)*TB + (size_t)tn)*D_IN);
      v2f D = xp2[0], E = xp2[1], F = xp2[2];
      xv0 = D[0]; xv1 = D[1]; xv2 = E[0]; xv3 = E[1]; xv4 = F[0]; xv5 = F[1];
    }
    BARRIER_LDS();  // b4
  }

  // final wout(TB-1): h(TB-1) sits in c0[0]
  if (wv == 7) wout_phase(c0[TB & 1], TB - 1);
}

extern "C" void kernel_launch(void* const* d_in, const int* in_sizes, int n_in,
                              void* d_out, int out_size, void* d_ws, size_t ws_size,
                              hipStream_t stream) {
  const float* x    = (const float*)d_in[0];
  const float* iF   = (const float*)d_in[1];
  const float* w10  = (const float*)d_in[2];
  const float* b10  = (const float*)d_in[3];
  const float* w20  = (const float*)d_in[4];
  const float* b20  = (const float*)d_in[5];
  const float* w11  = (const float*)d_in[6];
  const float* b11  = (const float*)d_in[7];
  const float* w21  = (const float*)d_in[8];
  const float* b21  = (const float*)d_in[9];
  const float* w12  = (const float*)d_in[10];
  const float* b12  = (const float*)d_in[11];
  const float* w22  = (const float*)d_in[12];
  const float* b22  = (const float*)d_in[13];
  const float* wa   = (const float*)d_in[14];
  const float* ba   = (const float*)d_in[15];
  const float* wb   = (const float*)d_in[16];
  const float* bb   = (const float*)d_in[17];
  const float* wo   = (const float*)d_in[18];

  float* outs = (float*)d_out;
  float* alph = outs + (size_t)NB*TB*DOUT;

  lmsc_kernel<<<NB/SPB, 512, 0, stream>>>(x, iF,
      w10, b10, w20, b20, w11, b11, w21, b21, w12, b12, w22, b22,
      wa, ba, wb, bb, wo, outs, alph);
}